// Round 6
// baseline (1649.837 us; speedup 1.0000x reference)
//
#include <hip/hip_runtime.h>

#define N_NODES 50000
#define DIM 128
#define BN_EPS 1e-5f

// ===========================================================================
// CSR build (once per call; graph identical across the 3 layers)
// ===========================================================================
__global__ __launch_bounds__(256) void edge_hist(const int* __restrict__ dst,
                                                 int* __restrict__ cnt, int E) {
  const int e = blockIdx.x * blockDim.x + threadIdx.x;
  if (e < E) atomicAdd(&cnt[dst[e]], 1);
}

__global__ __launch_bounds__(1024) void edge_scan(const int* __restrict__ cnt,
                                                  int* __restrict__ row_ptr) {
  __shared__ int part[1024];
  const int tid = threadIdx.x;
  const int per = (N_NODES + 1023) / 1024;  // 49
  const int start = tid * per;
  const int end = min(start + per, N_NODES);
  int s = 0;
  for (int i = start; i < end; ++i) s += cnt[i];
  part[tid] = s;
  __syncthreads();
  for (int off = 1; off < 1024; off <<= 1) {
    const int v = part[tid];
    const int u = (tid >= off) ? part[tid - off] : 0;
    __syncthreads();
    part[tid] = v + u;
    __syncthreads();
  }
  int run = (tid == 0) ? 0 : part[tid - 1];
  for (int i = start; i < end; ++i) {
    row_ptr[i] = run;
    run += cnt[i];
  }
  if (tid == 1023) row_ptr[N_NODES] = run;
}

__global__ __launch_bounds__(256) void edge_fill(const int* __restrict__ src,
                                                 const int* __restrict__ dst,
                                                 const int* __restrict__ row_ptr,
                                                 int* __restrict__ cur,
                                                 int* __restrict__ srcl, int E) {
  const int e = blockIdx.x * blockDim.x + threadIdx.x;
  if (e < E) {
    const int d = dst[e];
    const int pos = row_ptr[d] + atomicAdd(&cur[d], 1);
    srcl[pos] = src[e];
  }
}

// ===========================================================================
// Aggregation fused with GIN combine and (FUSE=1) the PREVIOUS layer's
// outer-BN + ReLU:  u = FUSE ? relu(a[c]*t + c[c]) : t
//   z[i] = (1+eps)*u[i] + sum_{j in nbrs(i)} relu(u[j])
// One wave per node; lane owns 2 columns. No atomics, no barriers.
// ===========================================================================
template <int FUSE>
__global__ __launch_bounds__(256) void aggregate_combine(
    const float* __restrict__ h, const int* __restrict__ rp,
    const int* __restrict__ srcl, const float* __restrict__ eps_l,
    const float* __restrict__ ac, float* __restrict__ z) {
  const int node =
      __builtin_amdgcn_readfirstlane(blockIdx.x * 4 + (threadIdx.x >> 6));
  if (node >= N_NODES) return;
  const int lane = threadIdx.x & 63;
  const int col = lane * 2;

  float2 av, cv;
  if (FUSE) {
    av.x = ac[col]; av.y = ac[col + 1];
    cv.x = ac[DIM + col]; cv.y = ac[DIM + col + 1];
  }
  const float epsv = 1.0f + *eps_l;

  float2 acc;
  {
    const float2 u =
        *reinterpret_cast<const float2*>(h + (size_t)node * DIM + col);
    float2 s;
    if (FUSE) {
      s.x = fmaxf(fmaf(av.x, u.x, cv.x), 0.f);
      s.y = fmaxf(fmaf(av.y, u.y, cv.y), 0.f);
    } else {
      s = u;  // layer 0 self term: raw x (no relu on self)
    }
    acc.x = epsv * s.x;
    acc.y = epsv * s.y;
  }

  int p = rp[node];
  const int pe = rp[node + 1];
  for (; p + 8 <= pe; p += 8) {
    int s[8];
#pragma unroll
    for (int i = 0; i < 8; ++i) s[i] = srcl[p + i];
    float2 v[8];
#pragma unroll
    for (int i = 0; i < 8; ++i)
      v[i] = *reinterpret_cast<const float2*>(h + (size_t)s[i] * DIM + col);
#pragma unroll
    for (int i = 0; i < 8; ++i) {
      float mx, my;
      if (FUSE) {
        mx = fmaxf(fmaf(av.x, v[i].x, cv.x), 0.f);
        my = fmaxf(fmaf(av.y, v[i].y, cv.y), 0.f);
      } else {
        mx = fmaxf(v[i].x, 0.f);
        my = fmaxf(v[i].y, 0.f);
      }
      acc.x += mx;
      acc.y += my;
    }
  }
  for (; p < pe; ++p) {
    const int s = srcl[p];
    const float2 v =
        *reinterpret_cast<const float2*>(h + (size_t)s * DIM + col);
    if (FUSE) {
      acc.x += fmaxf(fmaf(av.x, v.x, cv.x), 0.f);
      acc.y += fmaxf(fmaf(av.y, v.y, cv.y), 0.f);
    } else {
      acc.x += fmaxf(v.x, 0.f);
      acc.y += fmaxf(v.y, 0.f);
    }
  }
  *reinterpret_cast<float2*>(z + (size_t)node * DIM + col) = acc;
}

// ===========================================================================
// GEMM v3: lane<->row, W staged whole in LDS (64 KB), read via wave-uniform
// broadcast. One barrier total. Each lane owns 2 rows (r, r+64); wave covers
// 128 rows x 32 cols (col quarter = wave id). z streamed from global in 16-k
// double-buffered chunks. MODE 2: f=identity; MODE 1: f=relu(a[k]*x+c[k]).
// Epilogue: store rows, butterfly-reduce per-column sum/sumsq, 2 atomics per
// even lane into stats[].
// ===========================================================================
template <int MODE>
__global__ __launch_bounds__(256) void gemm_v3(
    const float* __restrict__ in, const float* __restrict__ ac,
    const float* __restrict__ W, const float* __restrict__ bias,
    float* __restrict__ out, float* __restrict__ stats) {
  __shared__ float w_lds[DIM * DIM];  // 64 KB

  const int tid = threadIdx.x;
  const int lane = tid & 63;
  const int colb = __builtin_amdgcn_readfirstlane((tid >> 6) * 32);
  const int r0 = blockIdx.x * 128 + lane;
  const int r1 = r0 + 64;
  const bool v0 = r0 < N_NODES;
  const bool v1 = r1 < N_NODES;
  const float* __restrict__ zp0 = in + (size_t)(v0 ? r0 : 0) * DIM;
  const float* __restrict__ zp1 = in + (size_t)(v1 ? r1 : 0) * DIM;

  float acc0[32], acc1[32];
#pragma unroll
  for (int j = 0; j < 32; ++j) { acc0[j] = 0.f; acc1[j] = 0.f; }

#define LOADZ(Z0, Z1, C)                                                     \
  {                                                                          \
    const int kb_ = (C) * 16;                                                \
    _Pragma("unroll") for (int q = 0; q < 4; ++q) {                          \
      Z0[q] = *reinterpret_cast<const float4*>(zp0 + kb_ + q * 4);           \
      Z1[q] = *reinterpret_cast<const float4*>(zp1 + kb_ + q * 4);           \
      if (MODE == 1) {                                                       \
        const float4 A_ = *reinterpret_cast<const float4*>(ac + kb_ + q * 4);\
        const float4 C_ =                                                    \
            *reinterpret_cast<const float4*>(ac + DIM + kb_ + q * 4);        \
        Z0[q].x = fmaxf(fmaf(A_.x, Z0[q].x, C_.x), 0.f);                     \
        Z0[q].y = fmaxf(fmaf(A_.y, Z0[q].y, C_.y), 0.f);                     \
        Z0[q].z = fmaxf(fmaf(A_.z, Z0[q].z, C_.z), 0.f);                     \
        Z0[q].w = fmaxf(fmaf(A_.w, Z0[q].w, C_.w), 0.f);                     \
        Z1[q].x = fmaxf(fmaf(A_.x, Z1[q].x, C_.x), 0.f);                     \
        Z1[q].y = fmaxf(fmaf(A_.y, Z1[q].y, C_.y), 0.f);                     \
        Z1[q].z = fmaxf(fmaf(A_.z, Z1[q].z, C_.z), 0.f);                     \
        Z1[q].w = fmaxf(fmaf(A_.w, Z1[q].w, C_.w), 0.f);                     \
      }                                                                      \
    }                                                                        \
  }

#define FMA_K(z0v, z1v, KIDX)                                                \
  {                                                                          \
    _Pragma("unroll") for (int jj = 0; jj < 8; ++jj) {                       \
      const float4 wf_ = *reinterpret_cast<const float4*>(                   \
          &w_lds[(KIDX) * DIM + colb + jj * 4]);                             \
      acc0[jj * 4 + 0] = fmaf(wf_.x, (z0v), acc0[jj * 4 + 0]);               \
      acc0[jj * 4 + 1] = fmaf(wf_.y, (z0v), acc0[jj * 4 + 1]);               \
      acc0[jj * 4 + 2] = fmaf(wf_.z, (z0v), acc0[jj * 4 + 2]);               \
      acc0[jj * 4 + 3] = fmaf(wf_.w, (z0v), acc0[jj * 4 + 3]);               \
      acc1[jj * 4 + 0] = fmaf(wf_.x, (z1v), acc1[jj * 4 + 0]);               \
      acc1[jj * 4 + 1] = fmaf(wf_.y, (z1v), acc1[jj * 4 + 1]);               \
      acc1[jj * 4 + 2] = fmaf(wf_.z, (z1v), acc1[jj * 4 + 2]);               \
      acc1[jj * 4 + 3] = fmaf(wf_.w, (z1v), acc1[jj * 4 + 3]);               \
    }                                                                        \
  }

#define COMPUTE(Z0, Z1, C)                                                   \
  {                                                                          \
    _Pragma("unroll") for (int q = 0; q < 4; ++q) {                          \
      const int k0_ = (C) * 16 + q * 4;                                      \
      FMA_K(Z0[q].x, Z1[q].x, k0_ + 0)                                       \
      FMA_K(Z0[q].y, Z1[q].y, k0_ + 1)                                       \
      FMA_K(Z0[q].z, Z1[q].z, k0_ + 2)                                       \
      FMA_K(Z0[q].w, Z1[q].w, k0_ + 3)                                       \
    }                                                                        \
  }

  // first z chunk issued before W staging so its latency overlaps
  float4 xa0[4], xa1[4], xb0[4], xb1[4];
  LOADZ(xa0, xa1, 0)

  // ---- stage all of W into LDS (linear copy, 16 float4 per thread)
#pragma unroll
  for (int it = 0; it < 16; ++it) {
    const int i4 = it * 256 + tid;
    *reinterpret_cast<float4*>(&w_lds[i4 * 4]) =
        *reinterpret_cast<const float4*>(&W[(size_t)i4 * 4]);
  }
  __syncthreads();  // the only barrier

#pragma unroll 1
  for (int c = 0; c < 8; c += 2) {
    LOADZ(xb0, xb1, c + 1)
    COMPUTE(xa0, xa1, c)
    if (c + 2 < 8) LOADZ(xa0, xa1, c + 2)
    COMPUTE(xb0, xb1, c + 1)
  }
#undef LOADZ
#undef FMA_K
#undef COMPUTE

  // ---- epilogue: bias, store, fused sum/sumsq butterfly, atomics
  const float* __restrict__ bb = bias + colb;
  float s[32], q[32];
#pragma unroll
  for (int j = 0; j < 32; ++j) {
    const float x0 = v0 ? (acc0[j] + bb[j]) : 0.f;
    const float x1 = v1 ? (acc1[j] + bb[j]) : 0.f;
    acc0[j] = x0;
    acc1[j] = x1;
    s[j] = x0 + x1;
    q[j] = x0 * x0 + x1 * x1;
  }
  if (v0) {
    float* op = out + (size_t)r0 * DIM + colb;
#pragma unroll
    for (int j4 = 0; j4 < 8; ++j4) {
      float4 o;
      o.x = acc0[j4 * 4 + 0]; o.y = acc0[j4 * 4 + 1];
      o.z = acc0[j4 * 4 + 2]; o.w = acc0[j4 * 4 + 3];
      *reinterpret_cast<float4*>(op + j4 * 4) = o;
    }
  }
  if (v1) {
    float* op = out + (size_t)r1 * DIM + colb;
#pragma unroll
    for (int j4 = 0; j4 < 8; ++j4) {
      float4 o;
      o.x = acc1[j4 * 4 + 0]; o.y = acc1[j4 * 4 + 1];
      o.z = acc1[j4 * 4 + 2]; o.w = acc1[j4 * 4 + 3];
      *reinterpret_cast<float4*>(op + j4 * 4) = o;
    }
  }
#define RSTEP(ARR, CNT, O)                                                   \
  {                                                                          \
    _Pragma("unroll") for (int jj = 0; jj < (CNT); ++jj) {                   \
      const bool hi_ = (lane & (O)) != 0;                                    \
      const float keep_ = hi_ ? ARR[jj + (CNT)] : ARR[jj];                   \
      const float send_ = hi_ ? ARR[jj] : ARR[jj + (CNT)];                   \
      ARR[jj] = keep_ + __shfl_xor(send_, (O));                              \
    }                                                                        \
  }
  RSTEP(s, 16, 32) RSTEP(q, 16, 32)
  RSTEP(s, 8, 16)  RSTEP(q, 8, 16)
  RSTEP(s, 4, 8)   RSTEP(q, 4, 8)
  RSTEP(s, 2, 4)   RSTEP(q, 2, 4)
  RSTEP(s, 1, 2)   RSTEP(q, 1, 2)
#undef RSTEP
  s[0] += __shfl_xor(s[0], 1);
  q[0] += __shfl_xor(q[0], 1);
  if ((lane & 1) == 0) {  // lane l holds totals for column colb + (l>>1)
    const int jc = colb + (lane >> 1);
    atomicAdd(&stats[jc], s[0]);
    atomicAdd(&stats[DIM + jc], q[0]);
  }
}

// ---------------------------------------------------------------------------
// Fold (sum, sumsq) -> (a = g*rsqrt(var+eps), c = b - mu*a). One block.
// ---------------------------------------------------------------------------
__global__ void bn_param(const float* __restrict__ stats,
                         const float* __restrict__ g,
                         const float* __restrict__ b, float* __restrict__ ac) {
  const int j = threadIdx.x;
  const float invN = 1.0f / (float)N_NODES;
  const float mu = stats[j] * invN;
  const float var = stats[DIM + j] * invN - mu * mu;
  const float a = g[j] * rsqrtf(var + BN_EPS);
  ac[j] = a;
  ac[DIM + j] = b[j] - mu * a;
}

// ---------------------------------------------------------------------------
// Final output only: out = a[k]*t + c[k] (no relu).
// ---------------------------------------------------------------------------
__global__ __launch_bounds__(256) void apply_bn(const float* __restrict__ t,
                                                const float* __restrict__ ac,
                                                float* __restrict__ out) {
  const int i = blockIdx.x * blockDim.x + threadIdx.x;
  const int k = (i * 4) & (DIM - 1);
  const float4 v = *reinterpret_cast<const float4*>(&t[(size_t)i * 4]);
  const float4 a = *reinterpret_cast<const float4*>(&ac[k]);
  const float4 c = *reinterpret_cast<const float4*>(&ac[DIM + k]);
  float4 r;
  r.x = fmaf(a.x, v.x, c.x);
  r.y = fmaf(a.y, v.y, c.y);
  r.z = fmaf(a.z, v.z, c.z);
  r.w = fmaf(a.w, v.w, c.w);
  *reinterpret_cast<float4*>(&out[(size_t)i * 4]) = r;
}

extern "C" void kernel_launch(void* const* d_in, const int* in_sizes, int n_in,
                              void* d_out, int out_size, void* d_ws,
                              size_t ws_size, hipStream_t stream) {
  const float* x = (const float*)d_in[0];
  const int* ei = (const int*)d_in[1];  // [2][E]: src = ei, dst = ei+E
  const float* eps = (const float*)d_in[2];
  const float* W1 = (const float*)d_in[3];
  const float* b1 = (const float*)d_in[4];
  const float* g1 = (const float*)d_in[5];
  const float* bb1 = (const float*)d_in[6];
  const float* W2 = (const float*)d_in[7];
  const float* b2 = (const float*)d_in[8];
  const float* g2 = (const float*)d_in[9];
  const float* bb2 = (const float*)d_in[10];

  const int E = in_sizes[1] / 2;
  const size_t ND = (size_t)N_NODES * DIM;

  float* bufA = (float*)d_ws;
  float* bufB = bufA + ND;
  float* stats = bufB + ND;          // 512 floats
  float* bnp = stats + 512;          // 512 floats (a1,c1 | a2,c2)
  int* cnt = (int*)(bnp + 512);      // [N]
  int* row_ptr = cnt + N_NODES;      // [N+1]
  int* cur = row_ptr + N_NODES + 1;  // [N]
  int* srcl = cur + N_NODES;         // [E]

  const int edge_grid = (E + 255) / 256;
  const int agg_grid = (N_NODES + 3) / 4;            // 12500, exact
  const int gemm_grid = (N_NODES + 127) / 128;       // 391
  const int apply_grid = (N_NODES * DIM / 4) / 256;  // 6250, exact

  // ---- CSR build
  hipMemsetAsync(cnt, 0, sizeof(int) * (size_t)N_NODES, stream);
  hipMemsetAsync(cur, 0, sizeof(int) * (size_t)N_NODES, stream);
  edge_hist<<<edge_grid, 256, 0, stream>>>(ei + E, cnt, E);
  edge_scan<<<1, 1024, 0, stream>>>(cnt, row_ptr);
  edge_fill<<<edge_grid, 256, 0, stream>>>(ei, ei + E, row_ptr, cur, srcl, E);

  const float* hin = x;   // aggregate input (x, then t2 of previous layer)
  float* zb = bufA;       // aggregate out / gemm1 in; gemm2 out
  float* tb = bufB;       // gemm1 out / gemm2 in
  for (int l = 0; l < 3; ++l) {
    hipMemsetAsync(stats, 0, sizeof(float) * 512, stream);
    if (l == 0)
      aggregate_combine<0><<<agg_grid, 256, 0, stream>>>(hin, row_ptr, srcl,
                                                         eps + l, nullptr, zb);
    else
      aggregate_combine<1><<<agg_grid, 256, 0, stream>>>(
          hin, row_ptr, srcl, eps + l, bnp + 256, zb);
    gemm_v3<2><<<gemm_grid, 256, 0, stream>>>(
        zb, nullptr, W1 + (size_t)l * DIM * DIM, b1 + l * DIM, tb, stats);
    bn_param<<<1, DIM, 0, stream>>>(stats, g1 + l * DIM, bb1 + l * DIM, bnp);
    gemm_v3<1><<<gemm_grid, 256, 0, stream>>>(
        tb, bnp, W2 + (size_t)l * DIM * DIM, b2 + l * DIM, zb, stats + 256);
    bn_param<<<1, DIM, 0, stream>>>(stats + 256, g2 + l * DIM, bb2 + l * DIM,
                                    bnp + 256);
    hin = zb;           // this layer's t2
    float* tmp = zb;    // ping-pong so next aggregate never writes its input
    zb = tb;
    tb = tmp;
  }
  apply_bn<<<apply_grid, 256, 0, stream>>>(hin, bnp + 256, (float*)d_out);
}

// Round 9
// 834.243 us; speedup vs baseline: 1.9776x; 1.9776x over previous
//
#include <hip/hip_runtime.h>

#define N_NODES 50000
#define DIM 128
#define BN_EPS 1e-5f

typedef short bf16x8 __attribute__((ext_vector_type(8)));
typedef float f32x4 __attribute__((ext_vector_type(4)));

__device__ __forceinline__ unsigned short f2bf(float x) {
  unsigned u = __float_as_uint(x);
  u += 0x7FFFu + ((u >> 16) & 1u);  // round-to-nearest-even
  return (unsigned short)(u >> 16);
}
__device__ __forceinline__ float bf2f(unsigned short h) {
  return __uint_as_float(((unsigned)h) << 16);
}

// ===========================================================================
// CSR build (once per call; graph identical across the 3 layers)
// ===========================================================================
__global__ __launch_bounds__(256) void edge_hist(const int* __restrict__ dst,
                                                 int* __restrict__ cnt, int E) {
  const int e = blockIdx.x * blockDim.x + threadIdx.x;
  if (e < E) atomicAdd(&cnt[dst[e]], 1);
}

__global__ __launch_bounds__(1024) void edge_scan(const int* __restrict__ cnt,
                                                  int* __restrict__ row_ptr) {
  __shared__ int part[1024];
  const int tid = threadIdx.x;
  const int per = (N_NODES + 1023) / 1024;  // 49
  const int start = tid * per;
  const int end = min(start + per, N_NODES);
  int s = 0;
  for (int i = start; i < end; ++i) s += cnt[i];
  part[tid] = s;
  __syncthreads();
  for (int off = 1; off < 1024; off <<= 1) {
    const int v = part[tid];
    const int u = (tid >= off) ? part[tid - off] : 0;
    __syncthreads();
    part[tid] = v + u;
    __syncthreads();
  }
  int run = (tid == 0) ? 0 : part[tid - 1];
  for (int i = start; i < end; ++i) {
    row_ptr[i] = run;
    run += cnt[i];
  }
  if (tid == 1023) row_ptr[N_NODES] = run;
}

__global__ __launch_bounds__(256) void edge_fill(const int* __restrict__ src,
                                                 const int* __restrict__ dst,
                                                 const int* __restrict__ row_ptr,
                                                 int* __restrict__ cur,
                                                 int* __restrict__ srcl, int E) {
  const int e = blockIdx.x * blockDim.x + threadIdx.x;
  if (e < E) {
    const int d = dst[e];
    const int pos = row_ptr[d] + atomicAdd(&cur[d], 1);
    srcl[pos] = src[e];
  }
}

// ===========================================================================
// Aggregation fused with GIN combine and (FUSE=1) the PREVIOUS layer's
// outer-BN + ReLU. Unchanged from round 4 (passing).
// ===========================================================================
template <int FUSE>
__global__ __launch_bounds__(256) void aggregate_combine(
    const float* __restrict__ h, const int* __restrict__ rp,
    const int* __restrict__ srcl, const float* __restrict__ eps_l,
    const float* __restrict__ ac, float* __restrict__ z) {
  const int node =
      __builtin_amdgcn_readfirstlane(blockIdx.x * 4 + (threadIdx.x >> 6));
  if (node >= N_NODES) return;
  const int lane = threadIdx.x & 63;
  const int col = lane * 2;

  float2 av, cv;
  if (FUSE) {
    av.x = ac[col]; av.y = ac[col + 1];
    cv.x = ac[DIM + col]; cv.y = ac[DIM + col + 1];
  }
  const float epsv = 1.0f + *eps_l;

  float2 acc;
  {
    const float2 u =
        *reinterpret_cast<const float2*>(h + (size_t)node * DIM + col);
    float2 s;
    if (FUSE) {
      s.x = fmaxf(fmaf(av.x, u.x, cv.x), 0.f);
      s.y = fmaxf(fmaf(av.y, u.y, cv.y), 0.f);
    } else {
      s = u;
    }
    acc.x = epsv * s.x;
    acc.y = epsv * s.y;
  }

  int p = rp[node];
  const int pe = rp[node + 1];
  for (; p + 8 <= pe; p += 8) {
    int s[8];
#pragma unroll
    for (int i = 0; i < 8; ++i) s[i] = srcl[p + i];
    float2 v[8];
#pragma unroll
    for (int i = 0; i < 8; ++i)
      v[i] = *reinterpret_cast<const float2*>(h + (size_t)s[i] * DIM + col);
#pragma unroll
    for (int i = 0; i < 8; ++i) {
      float mx, my;
      if (FUSE) {
        mx = fmaxf(fmaf(av.x, v[i].x, cv.x), 0.f);
        my = fmaxf(fmaf(av.y, v[i].y, cv.y), 0.f);
      } else {
        mx = fmaxf(v[i].x, 0.f);
        my = fmaxf(v[i].y, 0.f);
      }
      acc.x += mx;
      acc.y += my;
    }
  }
  for (; p < pe; ++p) {
    const int s = srcl[p];
    const float2 v =
        *reinterpret_cast<const float2*>(h + (size_t)s * DIM + col);
    if (FUSE) {
      acc.x += fmaxf(fmaf(av.x, v.x, cv.x), 0.f);
      acc.y += fmaxf(fmaf(av.y, v.y, cv.y), 0.f);
    } else {
      acc.x += fmaxf(v.x, 0.f);
      acc.y += fmaxf(v.y, 0.f);
    }
  }
  *reinterpret_cast<float2*>(z + (size_t)node * DIM + col) = acc;
}

// ===========================================================================
// prep_w: split fp32 W[k][j] into bf16 hi/lo, pre-swizzled into MFMA B-frag
// order: flat idx = (((s*8 + t)*64) + l)*8 + i, where k = s*32 + (l>>4)*8 + i,
// j = t*16 + (l&15). One thread per element; 64 blocks per matrix.
// ===========================================================================
__global__ __launch_bounds__(256) void prep_w(const float* __restrict__ W,
                                              unsigned short* __restrict__ hi,
                                              unsigned short* __restrict__ lo) {
  const int idx = blockIdx.x * 256 + threadIdx.x;  // 0..16383
  const int i = idx & 7;
  const int l = (idx >> 3) & 63;
  const int t = (idx >> 9) & 7;
  const int s = idx >> 12;
  const int k = s * 32 + ((l >> 4) << 3) + i;
  const int j = t * 16 + (l & 15);
  const float v = W[k * DIM + j];
  const unsigned short h = f2bf(v);
  hi[idx] = h;
  lo[idx] = f2bf(v - bf2f(h));
}

// ===========================================================================
// MFMA GEMM (split-bf16, 3 products): out = f(in) @ W + bias, fused BN stats.
//   MODE 2: f = identity;  MODE 1: f = relu(a[k]*x + c[k])
// Block: 256 thr = 4 waves; wave covers 32 rows x 128 cols via
// mfma_f32_16x16x32_bf16 (2 M-tiles x 8 N-tiles, acc = 64 VGPR).
// A-frags from global fp32 (8 contiguous floats/lane), split in-register.
// B-frags from prep_w arrays (1 dwordx4 each). No LDS, no barriers.
// Layouts: A/B: m|n = lane&15, k = (lane>>4)*8+i.  D: col=lane&15,
// row=(lane>>4)*4+j  [m89/m91-verified].
// ===========================================================================
template <int MODE>
__global__ __launch_bounds__(256, 2) void gemm_mfma(
    const float* __restrict__ in, const float* __restrict__ ac,
    const unsigned short* __restrict__ whi,
    const unsigned short* __restrict__ wlo, const float* __restrict__ bias,
    float* __restrict__ out, float* __restrict__ stats) {
  const int tid = threadIdx.x;
  const int lane = tid & 63;
  const int wv = tid >> 6;
  const int rbase = blockIdx.x * 128 + wv * 32;
  const int lr = lane & 15;         // A-row / B-col / D-col within tile
  const int lk = (lane >> 4) << 3;  // k offset within 32-k step

  f32x4 acc[2][8];
#pragma unroll
  for (int m = 0; m < 2; ++m)
#pragma unroll
    for (int t = 0; t < 8; ++t) acc[m][t] = (f32x4)(0.f);

  const int r0 = min(rbase + lr, N_NODES - 1);
  const int r1 = min(rbase + 16 + lr, N_NODES - 1);
  const float* __restrict__ z0 = in + (size_t)r0 * DIM + lk;
  const float* __restrict__ z1 = in + (size_t)r1 * DIM + lk;
  const bf16x8* __restrict__ bh = (const bf16x8*)whi + lane;
  const bf16x8* __restrict__ bl = (const bf16x8*)wlo + lane;

#pragma unroll 1
  for (int s = 0; s < 4; ++s) {
    const int k0 = s * 32;
    float a0v[8], a1v[8];
    {
      const float4 p0 = *reinterpret_cast<const float4*>(z0 + k0);
      const float4 p1 = *reinterpret_cast<const float4*>(z0 + k0 + 4);
      a0v[0] = p0.x; a0v[1] = p0.y; a0v[2] = p0.z; a0v[3] = p0.w;
      a0v[4] = p1.x; a0v[5] = p1.y; a0v[6] = p1.z; a0v[7] = p1.w;
      const float4 q0 = *reinterpret_cast<const float4*>(z1 + k0);
      const float4 q1 = *reinterpret_cast<const float4*>(z1 + k0 + 4);
      a1v[0] = q0.x; a1v[1] = q0.y; a1v[2] = q0.z; a1v[3] = q0.w;
      a1v[4] = q1.x; a1v[5] = q1.y; a1v[6] = q1.z; a1v[7] = q1.w;
    }
    if (MODE == 1) {
      const float4 A0 = *reinterpret_cast<const float4*>(ac + k0 + lk);
      const float4 A1 = *reinterpret_cast<const float4*>(ac + k0 + lk + 4);
      const float4 C0 = *reinterpret_cast<const float4*>(ac + DIM + k0 + lk);
      const float4 C1 =
          *reinterpret_cast<const float4*>(ac + DIM + k0 + lk + 4);
      float aa[8], cc[8];
      aa[0] = A0.x; aa[1] = A0.y; aa[2] = A0.z; aa[3] = A0.w;
      aa[4] = A1.x; aa[5] = A1.y; aa[6] = A1.z; aa[7] = A1.w;
      cc[0] = C0.x; cc[1] = C0.y; cc[2] = C0.z; cc[3] = C0.w;
      cc[4] = C1.x; cc[5] = C1.y; cc[6] = C1.z; cc[7] = C1.w;
#pragma unroll
      for (int i = 0; i < 8; ++i) {
        a0v[i] = fmaxf(fmaf(aa[i], a0v[i], cc[i]), 0.f);
        a1v[i] = fmaxf(fmaf(aa[i], a1v[i], cc[i]), 0.f);
      }
    }
    bf16x8 ah0, al0, ah1, al1;
#pragma unroll
    for (int i = 0; i < 8; ++i) {
      unsigned short h = f2bf(a0v[i]);
      ah0[i] = (short)h;
      al0[i] = (short)f2bf(a0v[i] - bf2f(h));
      h = f2bf(a1v[i]);
      ah1[i] = (short)h;
      al1[i] = (short)f2bf(a1v[i] - bf2f(h));
    }
#pragma unroll
    for (int t = 0; t < 8; ++t) {
      const bf16x8 bhv = bh[(s * 8 + t) * 64];
      const bf16x8 blv = bl[(s * 8 + t) * 64];
      acc[0][t] =
          __builtin_amdgcn_mfma_f32_16x16x32_bf16(ah0, bhv, acc[0][t], 0, 0, 0);
      acc[0][t] =
          __builtin_amdgcn_mfma_f32_16x16x32_bf16(al0, bhv, acc[0][t], 0, 0, 0);
      acc[0][t] =
          __builtin_amdgcn_mfma_f32_16x16x32_bf16(ah0, blv, acc[0][t], 0, 0, 0);
      acc[1][t] =
          __builtin_amdgcn_mfma_f32_16x16x32_bf16(ah1, bhv, acc[1][t], 0, 0, 0);
      acc[1][t] =
          __builtin_amdgcn_mfma_f32_16x16x32_bf16(al1, bhv, acc[1][t], 0, 0, 0);
      acc[1][t] =
          __builtin_amdgcn_mfma_f32_16x16x32_bf16(ah1, blv, acc[1][t], 0, 0, 0);
    }
  }

  // ---- epilogue: bias, store, per-column stats
  float bj[8];
#pragma unroll
  for (int t = 0; t < 8; ++t) bj[t] = bias[t * 16 + lr];
  float cs[8], cq[8];
#pragma unroll
  for (int t = 0; t < 8; ++t) { cs[t] = 0.f; cq[t] = 0.f; }
#pragma unroll
  for (int m = 0; m < 2; ++m) {
    const int rb2 = rbase + m * 16 + ((lane >> 4) << 2);
#pragma unroll
    for (int t = 0; t < 8; ++t) {
#pragma unroll
      for (int j = 0; j < 4; ++j) {
        const int rr = rb2 + j;
        const float v = acc[m][t][j] + bj[t];
        if (rr < N_NODES) {
          out[(size_t)rr * DIM + t * 16 + lr] = v;
          cs[t] += v;
          cq[t] += v * v;
        }
      }
    }
  }
#pragma unroll
  for (int t = 0; t < 8; ++t) {
    cs[t] += __shfl_xor(cs[t], 16);
    cs[t] += __shfl_xor(cs[t], 32);
    cq[t] += __shfl_xor(cq[t], 16);
    cq[t] += __shfl_xor(cq[t], 32);
  }
  if (lane < 16) {
#pragma unroll
    for (int t = 0; t < 8; ++t) {
      atomicAdd(&stats[t * 16 + lane], cs[t]);
      atomicAdd(&stats[DIM + t * 16 + lane], cq[t]);
    }
  }
}

// ---------------------------------------------------------------------------
// Fold (sum, sumsq) -> (a = g*rsqrt(var+eps), c = b - mu*a). One block.
// ---------------------------------------------------------------------------
__global__ void bn_param(const float* __restrict__ stats,
                         const float* __restrict__ g,
                         const float* __restrict__ b, float* __restrict__ ac) {
  const int j = threadIdx.x;
  const float invN = 1.0f / (float)N_NODES;
  const float mu = stats[j] * invN;
  const float var = stats[DIM + j] * invN - mu * mu;
  const float a = g[j] * rsqrtf(var + BN_EPS);
  ac[j] = a;
  ac[DIM + j] = b[j] - mu * a;
}

// ---------------------------------------------------------------------------
// Final output only: out = a[k]*t + c[k] (no relu).
// ---------------------------------------------------------------------------
__global__ __launch_bounds__(256) void apply_bn(const float* __restrict__ t,
                                                const float* __restrict__ ac,
                                                float* __restrict__ out) {
  const int i = blockIdx.x * blockDim.x + threadIdx.x;
  const int k = (i * 4) & (DIM - 1);
  const float4 v = *reinterpret_cast<const float4*>(&t[(size_t)i * 4]);
  const float4 a = *reinterpret_cast<const float4*>(&ac[k]);
  const float4 c = *reinterpret_cast<const float4*>(&ac[DIM + k]);
  float4 r;
  r.x = fmaf(a.x, v.x, c.x);
  r.y = fmaf(a.y, v.y, c.y);
  r.z = fmaf(a.z, v.z, c.z);
  r.w = fmaf(a.w, v.w, c.w);
  *reinterpret_cast<float4*>(&out[(size_t)i * 4]) = r;
}

extern "C" void kernel_launch(void* const* d_in, const int* in_sizes, int n_in,
                              void* d_out, int out_size, void* d_ws,
                              size_t ws_size, hipStream_t stream) {
  const float* x = (const float*)d_in[0];
  const int* ei = (const int*)d_in[1];  // [2][E]: src = ei, dst = ei+E
  const float* eps = (const float*)d_in[2];
  const float* W1 = (const float*)d_in[3];
  const float* b1 = (const float*)d_in[4];
  const float* g1 = (const float*)d_in[5];
  const float* bb1 = (const float*)d_in[6];
  const float* W2 = (const float*)d_in[7];
  const float* b2 = (const float*)d_in[8];
  const float* g2 = (const float*)d_in[9];
  const float* bb2 = (const float*)d_in[10];

  const int E = in_sizes[1] / 2;
  const size_t ND = (size_t)N_NODES * DIM;

  float* bufA = (float*)d_ws;
  float* bufB = bufA + ND;
  float* stats = bufB + ND;          // 512 floats
  float* bnp = stats + 512;          // 512 floats (a1,c1 | a2,c2)
  int* cnt = (int*)(bnp + 512);      // [N]
  int* row_ptr = cnt + N_NODES;      // [N+1]
  int* cur = row_ptr + N_NODES + 1;  // [N]
  int* srcl = cur + N_NODES;         // [E]
  unsigned short* wf = (unsigned short*)(srcl + E);  // 6 x (16384 hi + 16384 lo)

  const int edge_grid = (E + 255) / 256;
  const int agg_grid = (N_NODES + 3) / 4;            // 12500, exact
  const int gemm_grid = (N_NODES + 127) / 128;       // 391
  const int apply_grid = (N_NODES * DIM / 4) / 256;  // 6250, exact

  // ---- W fragment prep (6 matrices, graph-independent)
  for (int l = 0; l < 3; ++l) {
    unsigned short* f1 = wf + (size_t)(2 * l) * 32768;
    unsigned short* f2 = wf + (size_t)(2 * l + 1) * 32768;
    prep_w<<<64, 256, 0, stream>>>(W1 + (size_t)l * DIM * DIM, f1, f1 + 16384);
    prep_w<<<64, 256, 0, stream>>>(W2 + (size_t)l * DIM * DIM, f2, f2 + 16384);
  }

  // ---- CSR build
  hipMemsetAsync(cnt, 0, sizeof(int) * (size_t)N_NODES, stream);
  hipMemsetAsync(cur, 0, sizeof(int) * (size_t)N_NODES, stream);
  edge_hist<<<edge_grid, 256, 0, stream>>>(ei + E, cnt, E);
  edge_scan<<<1, 1024, 0, stream>>>(cnt, row_ptr);
  edge_fill<<<edge_grid, 256, 0, stream>>>(ei, ei + E, row_ptr, cur, srcl, E);

  const float* hin = x;   // aggregate input (x, then t2 of previous layer)
  float* zb = bufA;       // aggregate out / gemm1 in; gemm2 out
  float* tb = bufB;       // gemm1 out / gemm2 in
  for (int l = 0; l < 3; ++l) {
    unsigned short* f1 = wf + (size_t)(2 * l) * 32768;
    unsigned short* f2 = wf + (size_t)(2 * l + 1) * 32768;
    hipMemsetAsync(stats, 0, sizeof(float) * 512, stream);
    if (l == 0)
      aggregate_combine<0><<<agg_grid, 256, 0, stream>>>(hin, row_ptr, srcl,
                                                         eps + l, nullptr, zb);
    else
      aggregate_combine<1><<<agg_grid, 256, 0, stream>>>(
          hin, row_ptr, srcl, eps + l, bnp + 256, zb);
    gemm_mfma<2><<<gemm_grid, 256, 0, stream>>>(zb, nullptr, f1, f1 + 16384,
                                                b1 + l * DIM, tb, stats);
    bn_param<<<1, DIM, 0, stream>>>(stats, g1 + l * DIM, bb1 + l * DIM, bnp);
    gemm_mfma<1><<<gemm_grid, 256, 0, stream>>>(tb, bnp, f2, f2 + 16384,
                                                b2 + l * DIM, zb, stats + 256);
    bn_param<<<1, DIM, 0, stream>>>(stats + 256, g2 + l * DIM, bb2 + l * DIM,
                                    bnp + 256);
    hin = zb;           // this layer's t2
    float* tmp = zb;    // ping-pong so next aggregate never writes its input
    zb = tb;
    tb = tmp;
  }
  apply_bn<<<apply_grid, 256, 0, stream>>>(hin, bnp + 256, (float*)d_out);
}

// Round 10
// 765.496 us; speedup vs baseline: 2.1553x; 1.0898x over previous
//
#include <hip/hip_runtime.h>

#define N_NODES 50000
#define DIM 128
#define BN_EPS 1e-5f
#define SCAN_B 49  // ceil(N_NODES / 1024)

typedef short bf16x8 __attribute__((ext_vector_type(8)));
typedef float f32x4 __attribute__((ext_vector_type(4)));

__device__ __forceinline__ unsigned short f2bf(float x) {
  unsigned u = __float_as_uint(x);
  u += 0x7FFFu + ((u >> 16) & 1u);  // round-to-nearest-even
  return (unsigned short)(u >> 16);
}
__device__ __forceinline__ float bf2f(unsigned short h) {
  return __uint_as_float(((unsigned)h) << 16);
}

// ===========================================================================
// CSR build (once per call; graph identical across the 3 layers)
// ===========================================================================
__global__ __launch_bounds__(256) void edge_hist(const int* __restrict__ dst,
                                                 int* __restrict__ cnt, int E) {
  const int e = blockIdx.x * blockDim.x + threadIdx.x;
  if (e < E) atomicAdd(&cnt[dst[e]], 1);
}

// Parallel exclusive scan, stage 1: per-block (1024 elts) local exclusive
// prefix into row_ptr, block total into bsum. 49 blocks x 256 thr x 4 elts.
__global__ __launch_bounds__(256) void scan1(const int* __restrict__ cnt,
                                             int* __restrict__ row_ptr,
                                             int* __restrict__ bsum) {
  __shared__ int lds[256];
  const int tid = threadIdx.x;
  const int base = blockIdx.x * 1024 + tid * 4;
  int v0 = 0, v1 = 0, v2 = 0, v3 = 0;
  if (base + 3 < N_NODES) {
    const int4 c4 = *reinterpret_cast<const int4*>(cnt + base);
    v0 = c4.x; v1 = c4.y; v2 = c4.z; v3 = c4.w;
  } else if (base < N_NODES) {
    v0 = cnt[base];
    if (base + 1 < N_NODES) v1 = cnt[base + 1];
    if (base + 2 < N_NODES) v2 = cnt[base + 2];
    if (base + 3 < N_NODES) v3 = cnt[base + 3];
  }
  lds[tid] = v0 + v1 + v2 + v3;
  __syncthreads();
  for (int off = 1; off < 256; off <<= 1) {
    const int val = lds[tid];
    const int add = (tid >= off) ? lds[tid - off] : 0;
    __syncthreads();
    lds[tid] = val + add;  // inclusive scan of per-thread sums
    __syncthreads();
  }
  const int pre = tid ? lds[tid - 1] : 0;
  if (base < N_NODES) {
    row_ptr[base] = pre;
    if (base + 1 < N_NODES) row_ptr[base + 1] = pre + v0;
    if (base + 2 < N_NODES) row_ptr[base + 2] = pre + v0 + v1;
    if (base + 3 < N_NODES) row_ptr[base + 3] = pre + v0 + v1 + v2;
  }
  if (tid == 255) bsum[blockIdx.x] = lds[255];
}

// Stage 2: one wave scans the 49 block sums -> exclusive offsets; writes total.
__global__ __launch_bounds__(64) void scan2(const int* __restrict__ bsum,
                                            int* __restrict__ boff,
                                            int* __restrict__ row_ptr_tail) {
  __shared__ int lds[64];
  const int t = threadIdx.x;
  const int v = (t < SCAN_B) ? bsum[t] : 0;
  lds[t] = v;
  __syncthreads();
  for (int off = 1; off < 64; off <<= 1) {
    const int val = lds[t];
    const int add = (t >= off) ? lds[t - off] : 0;
    __syncthreads();
    lds[t] = val + add;
    __syncthreads();
  }
  if (t < SCAN_B) boff[t] = lds[t] - v;       // exclusive block offset
  if (t == SCAN_B - 1) row_ptr_tail[0] = lds[t];  // row_ptr[N] = E
}

// Stage 3: add block offsets in place.
__global__ __launch_bounds__(256) void scan3(int* __restrict__ row_ptr,
                                             const int* __restrict__ boff) {
  const int i = blockIdx.x * 1024 + threadIdx.x * 4;
  const int off = boff[blockIdx.x];
  if (i + 3 < N_NODES) {
    int4 r = *reinterpret_cast<int4*>(row_ptr + i);
    r.x += off; r.y += off; r.z += off; r.w += off;
    *reinterpret_cast<int4*>(row_ptr + i) = r;
  } else if (i < N_NODES) {
    for (int k = i; k < N_NODES; ++k) row_ptr[k] += off;
  }
}

__global__ __launch_bounds__(256) void edge_fill(const int* __restrict__ src,
                                                 const int* __restrict__ dst,
                                                 const int* __restrict__ row_ptr,
                                                 int* __restrict__ cur,
                                                 int* __restrict__ srcl, int E) {
  const int e = blockIdx.x * blockDim.x + threadIdx.x;
  if (e < E) {
    const int d = dst[e];
    const int pos = row_ptr[d] + atomicAdd(&cur[d], 1);
    srcl[pos] = src[e];
  }
}

// ===========================================================================
// Aggregation fused with GIN combine; FUSE=1 additionally applies the
// PREVIOUS layer's outer BN (computed inline from stats) + ReLU.
// ===========================================================================
template <int FUSE>
__global__ __launch_bounds__(256) void aggregate_combine(
    const float* __restrict__ h, const int* __restrict__ rp,
    const int* __restrict__ srcl, const float* __restrict__ eps_l,
    const float* __restrict__ st, const float* __restrict__ gg,
    const float* __restrict__ bg, float* __restrict__ z) {
  const int node =
      __builtin_amdgcn_readfirstlane(blockIdx.x * 4 + (threadIdx.x >> 6));
  if (node >= N_NODES) return;
  const int lane = threadIdx.x & 63;
  const int col = lane * 2;

  float2 av, cv;
  if (FUSE) {  // a = g*rsqrt(var+eps), c = b - mu*a, from raw stats
    const float invN = 1.0f / (float)N_NODES;
    const float mu0 = st[col] * invN;
    const float mu1 = st[col + 1] * invN;
    const float va0 = fmaf(-mu0, mu0, st[DIM + col] * invN);
    const float va1 = fmaf(-mu1, mu1, st[DIM + col + 1] * invN);
    av.x = gg[col] * rsqrtf(va0 + BN_EPS);
    av.y = gg[col + 1] * rsqrtf(va1 + BN_EPS);
    cv.x = fmaf(-mu0, av.x, bg[col]);
    cv.y = fmaf(-mu1, av.y, bg[col + 1]);
  }
  const float epsv = 1.0f + *eps_l;

  float2 acc;
  {
    const float2 u =
        *reinterpret_cast<const float2*>(h + (size_t)node * DIM + col);
    float2 s;
    if (FUSE) {
      s.x = fmaxf(fmaf(av.x, u.x, cv.x), 0.f);
      s.y = fmaxf(fmaf(av.y, u.y, cv.y), 0.f);
    } else {
      s = u;  // layer 0 self term: raw x (no relu on self)
    }
    acc.x = epsv * s.x;
    acc.y = epsv * s.y;
  }

  int p = rp[node];
  const int pe = rp[node + 1];
  for (; p + 8 <= pe; p += 8) {
    int s[8];
#pragma unroll
    for (int i = 0; i < 8; ++i) s[i] = srcl[p + i];
    float2 v[8];
#pragma unroll
    for (int i = 0; i < 8; ++i)
      v[i] = *reinterpret_cast<const float2*>(h + (size_t)s[i] * DIM + col);
#pragma unroll
    for (int i = 0; i < 8; ++i) {
      float mx, my;
      if (FUSE) {
        mx = fmaxf(fmaf(av.x, v[i].x, cv.x), 0.f);
        my = fmaxf(fmaf(av.y, v[i].y, cv.y), 0.f);
      } else {
        mx = fmaxf(v[i].x, 0.f);
        my = fmaxf(v[i].y, 0.f);
      }
      acc.x += mx;
      acc.y += my;
    }
  }
  for (; p < pe; ++p) {
    const int s = srcl[p];
    const float2 v =
        *reinterpret_cast<const float2*>(h + (size_t)s * DIM + col);
    if (FUSE) {
      acc.x += fmaxf(fmaf(av.x, v.x, cv.x), 0.f);
      acc.y += fmaxf(fmaf(av.y, v.y, cv.y), 0.f);
    } else {
      acc.x += fmaxf(v.x, 0.f);
      acc.y += fmaxf(v.y, 0.f);
    }
  }
  *reinterpret_cast<float2*>(z + (size_t)node * DIM + col) = acc;
}

// ===========================================================================
// prep_w: split fp32 W[k][j] into bf16 hi/lo, pre-swizzled into MFMA B-frag
// order: flat idx = (((s*8 + t)*64) + l)*8 + i, where k = s*32 + (l>>4)*8 + i,
// j = t*16 + (l&15).
// ===========================================================================
__global__ __launch_bounds__(256) void prep_w(const float* __restrict__ W,
                                              unsigned short* __restrict__ hi,
                                              unsigned short* __restrict__ lo) {
  const int idx = blockIdx.x * 256 + threadIdx.x;  // 0..16383
  const int i = idx & 7;
  const int l = (idx >> 3) & 63;
  const int t = (idx >> 9) & 7;
  const int s = idx >> 12;
  const int k = s * 32 + ((l >> 4) << 3) + i;
  const int j = t * 16 + (l & 15);
  const float v = W[k * DIM + j];
  const unsigned short h = f2bf(v);
  hi[idx] = h;
  lo[idx] = f2bf(v - bf2f(h));
}

// ===========================================================================
// MFMA GEMM (split-bf16, 3 products): out = f(in) @ W + bias, fused BN stats.
//   MODE 2: f = identity;  MODE 1: f = relu(a[k]*x + c[k]), a/c from raw
//   stats (ist) + gamma (ig) + beta (ib), computed inline.
// Unchanged structure from round 9 (passing).
// ===========================================================================
template <int MODE>
__global__ __launch_bounds__(256, 2) void gemm_mfma(
    const float* __restrict__ in, const float* __restrict__ ist,
    const float* __restrict__ ig, const float* __restrict__ ib,
    const unsigned short* __restrict__ whi,
    const unsigned short* __restrict__ wlo, const float* __restrict__ bias,
    float* __restrict__ out, float* __restrict__ stats) {
  const int tid = threadIdx.x;
  const int lane = tid & 63;
  const int wv = tid >> 6;
  const int rbase = blockIdx.x * 128 + wv * 32;
  const int lr = lane & 15;         // A-row / B-col / D-col within tile
  const int lk = (lane >> 4) << 3;  // k offset within 32-k step

  f32x4 acc[2][8];
#pragma unroll
  for (int m = 0; m < 2; ++m)
#pragma unroll
    for (int t = 0; t < 8; ++t) acc[m][t] = (f32x4)(0.f);

  const int r0 = min(rbase + lr, N_NODES - 1);
  const int r1 = min(rbase + 16 + lr, N_NODES - 1);
  const float* __restrict__ z0 = in + (size_t)r0 * DIM + lk;
  const float* __restrict__ z1 = in + (size_t)r1 * DIM + lk;
  const bf16x8* __restrict__ bh = (const bf16x8*)whi + lane;
  const bf16x8* __restrict__ bl = (const bf16x8*)wlo + lane;

#pragma unroll 1
  for (int s = 0; s < 4; ++s) {
    const int k0 = s * 32;
    float a0v[8], a1v[8];
    {
      const float4 p0 = *reinterpret_cast<const float4*>(z0 + k0);
      const float4 p1 = *reinterpret_cast<const float4*>(z0 + k0 + 4);
      a0v[0] = p0.x; a0v[1] = p0.y; a0v[2] = p0.z; a0v[3] = p0.w;
      a0v[4] = p1.x; a0v[5] = p1.y; a0v[6] = p1.z; a0v[7] = p1.w;
      const float4 q0 = *reinterpret_cast<const float4*>(z1 + k0);
      const float4 q1 = *reinterpret_cast<const float4*>(z1 + k0 + 4);
      a1v[0] = q0.x; a1v[1] = q0.y; a1v[2] = q0.z; a1v[3] = q0.w;
      a1v[4] = q1.x; a1v[5] = q1.y; a1v[6] = q1.z; a1v[7] = q1.w;
    }
    if (MODE == 1) {
      const float invN = 1.0f / (float)N_NODES;
      const float4 S0 = *reinterpret_cast<const float4*>(ist + k0 + lk);
      const float4 S1 = *reinterpret_cast<const float4*>(ist + k0 + lk + 4);
      const float4 Q0 = *reinterpret_cast<const float4*>(ist + DIM + k0 + lk);
      const float4 Q1 =
          *reinterpret_cast<const float4*>(ist + DIM + k0 + lk + 4);
      const float4 G0 = *reinterpret_cast<const float4*>(ig + k0 + lk);
      const float4 G1 = *reinterpret_cast<const float4*>(ig + k0 + lk + 4);
      const float4 B0 = *reinterpret_cast<const float4*>(ib + k0 + lk);
      const float4 B1 = *reinterpret_cast<const float4*>(ib + k0 + lk + 4);
      float ss[8], qq[8], gv[8], bv[8];
      ss[0] = S0.x; ss[1] = S0.y; ss[2] = S0.z; ss[3] = S0.w;
      ss[4] = S1.x; ss[5] = S1.y; ss[6] = S1.z; ss[7] = S1.w;
      qq[0] = Q0.x; qq[1] = Q0.y; qq[2] = Q0.z; qq[3] = Q0.w;
      qq[4] = Q1.x; qq[5] = Q1.y; qq[6] = Q1.z; qq[7] = Q1.w;
      gv[0] = G0.x; gv[1] = G0.y; gv[2] = G0.z; gv[3] = G0.w;
      gv[4] = G1.x; gv[5] = G1.y; gv[6] = G1.z; gv[7] = G1.w;
      bv[0] = B0.x; bv[1] = B0.y; bv[2] = B0.z; bv[3] = B0.w;
      bv[4] = B1.x; bv[5] = B1.y; bv[6] = B1.z; bv[7] = B1.w;
#pragma unroll
      for (int i = 0; i < 8; ++i) {
        const float mu = ss[i] * invN;
        const float var = fmaf(-mu, mu, qq[i] * invN);
        const float a = gv[i] * rsqrtf(var + BN_EPS);
        const float c = fmaf(-mu, a, bv[i]);
        a0v[i] = fmaxf(fmaf(a, a0v[i], c), 0.f);
        a1v[i] = fmaxf(fmaf(a, a1v[i], c), 0.f);
      }
    }
    bf16x8 ah0, al0, ah1, al1;
#pragma unroll
    for (int i = 0; i < 8; ++i) {
      unsigned short h = f2bf(a0v[i]);
      ah0[i] = (short)h;
      al0[i] = (short)f2bf(a0v[i] - bf2f(h));
      h = f2bf(a1v[i]);
      ah1[i] = (short)h;
      al1[i] = (short)f2bf(a1v[i] - bf2f(h));
    }
#pragma unroll
    for (int t = 0; t < 8; ++t) {
      const bf16x8 bhv = bh[(s * 8 + t) * 64];
      const bf16x8 blv = bl[(s * 8 + t) * 64];
      acc[0][t] =
          __builtin_amdgcn_mfma_f32_16x16x32_bf16(ah0, bhv, acc[0][t], 0, 0, 0);
      acc[0][t] =
          __builtin_amdgcn_mfma_f32_16x16x32_bf16(al0, bhv, acc[0][t], 0, 0, 0);
      acc[0][t] =
          __builtin_amdgcn_mfma_f32_16x16x32_bf16(ah0, blv, acc[0][t], 0, 0, 0);
      acc[1][t] =
          __builtin_amdgcn_mfma_f32_16x16x32_bf16(ah1, bhv, acc[1][t], 0, 0, 0);
      acc[1][t] =
          __builtin_amdgcn_mfma_f32_16x16x32_bf16(al1, bhv, acc[1][t], 0, 0, 0);
      acc[1][t] =
          __builtin_amdgcn_mfma_f32_16x16x32_bf16(ah1, blv, acc[1][t], 0, 0, 0);
    }
  }

  // ---- epilogue: bias, store, per-column stats
  float bj[8];
#pragma unroll
  for (int t = 0; t < 8; ++t) bj[t] = bias[t * 16 + lr];
  float cs[8], cq[8];
#pragma unroll
  for (int t = 0; t < 8; ++t) { cs[t] = 0.f; cq[t] = 0.f; }
#pragma unroll
  for (int m = 0; m < 2; ++m) {
    const int rb2 = rbase + m * 16 + ((lane >> 4) << 2);
#pragma unroll
    for (int t = 0; t < 8; ++t) {
#pragma unroll
      for (int j = 0; j < 4; ++j) {
        const int rr = rb2 + j;
        const float v = acc[m][t][j] + bj[t];
        if (rr < N_NODES) {
          out[(size_t)rr * DIM + t * 16 + lr] = v;
          cs[t] += v;
          cq[t] += v * v;
        }
      }
    }
  }
#pragma unroll
  for (int t = 0; t < 8; ++t) {
    cs[t] += __shfl_xor(cs[t], 16);
    cs[t] += __shfl_xor(cs[t], 32);
    cq[t] += __shfl_xor(cq[t], 16);
    cq[t] += __shfl_xor(cq[t], 32);
  }
  if (lane < 16) {
#pragma unroll
    for (int t = 0; t < 8; ++t) {
      atomicAdd(&stats[t * 16 + lane], cs[t]);
      atomicAdd(&stats[DIM + t * 16 + lane], cq[t]);
    }
  }
}

// ---------------------------------------------------------------------------
// Final output: out = a[k]*t + c[k] (no relu), a/c computed inline from stats.
// ---------------------------------------------------------------------------
__global__ __launch_bounds__(256) void apply_bn(const float* __restrict__ t,
                                                const float* __restrict__ st,
                                                const float* __restrict__ gg,
                                                const float* __restrict__ bg,
                                                float* __restrict__ out) {
  const int i = blockIdx.x * blockDim.x + threadIdx.x;
  const int k = (i * 4) & (DIM - 1);
  const float invN = 1.0f / (float)N_NODES;
  const float4 S = *reinterpret_cast<const float4*>(&st[k]);
  const float4 Q = *reinterpret_cast<const float4*>(&st[DIM + k]);
  const float4 G = *reinterpret_cast<const float4*>(&gg[k]);
  const float4 B = *reinterpret_cast<const float4*>(&bg[k]);
  const float4 v = *reinterpret_cast<const float4*>(&t[(size_t)i * 4]);
  float4 r;
  {
    const float mu = S.x * invN;
    const float a = G.x * rsqrtf(fmaf(-mu, mu, Q.x * invN) + BN_EPS);
    r.x = fmaf(a, v.x, fmaf(-mu, a, B.x));
  }
  {
    const float mu = S.y * invN;
    const float a = G.y * rsqrtf(fmaf(-mu, mu, Q.y * invN) + BN_EPS);
    r.y = fmaf(a, v.y, fmaf(-mu, a, B.y));
  }
  {
    const float mu = S.z * invN;
    const float a = G.z * rsqrtf(fmaf(-mu, mu, Q.z * invN) + BN_EPS);
    r.z = fmaf(a, v.z, fmaf(-mu, a, B.z));
  }
  {
    const float mu = S.w * invN;
    const float a = G.w * rsqrtf(fmaf(-mu, mu, Q.w * invN) + BN_EPS);
    r.w = fmaf(a, v.w, fmaf(-mu, a, B.w));
  }
  *reinterpret_cast<float4*>(&out[(size_t)i * 4]) = r;
}

extern "C" void kernel_launch(void* const* d_in, const int* in_sizes, int n_in,
                              void* d_out, int out_size, void* d_ws,
                              size_t ws_size, hipStream_t stream) {
  const float* x = (const float*)d_in[0];
  const int* ei = (const int*)d_in[1];  // [2][E]: src = ei, dst = ei+E
  const float* eps = (const float*)d_in[2];
  const float* W1 = (const float*)d_in[3];
  const float* b1 = (const float*)d_in[4];
  const float* g1 = (const float*)d_in[5];
  const float* bb1 = (const float*)d_in[6];
  const float* W2 = (const float*)d_in[7];
  const float* b2 = (const float*)d_in[8];
  const float* g2 = (const float*)d_in[9];
  const float* bb2 = (const float*)d_in[10];

  const int E = in_sizes[1] / 2;
  const size_t ND = (size_t)N_NODES * DIM;

  float* bufA = (float*)d_ws;
  float* bufB = bufA + ND;
  float* stats = bufB + ND;  // 3 layers x 512 (sum1,sq1,sum2,sq2)
  unsigned short* wf = (unsigned short*)(stats + 1536);  // 6 x 32768, 16B-align
  int* cnt = (int*)(wf + 6 * 32768);  // [N]
  int* row_ptr = cnt + N_NODES;       // [N+1]
  int* cur = row_ptr + N_NODES + 1;   // [N]
  int* srcl = cur + N_NODES;          // [E]
  int* bsum = srcl + E;               // [64]
  int* boff = bsum + 64;              // [64]

  const int edge_grid = (E + 255) / 256;
  const int agg_grid = (N_NODES + 3) / 4;            // 12500, exact
  const int gemm_grid = (N_NODES + 127) / 128;       // 391
  const int apply_grid = (N_NODES * DIM / 4) / 256;  // 6250, exact

  // ---- W fragment prep (6 matrices)
  for (int l = 0; l < 3; ++l) {
    unsigned short* f1 = wf + (size_t)(2 * l) * 32768;
    unsigned short* f2 = wf + (size_t)(2 * l + 1) * 32768;
    prep_w<<<64, 256, 0, stream>>>(W1 + (size_t)l * DIM * DIM, f1, f1 + 16384);
    prep_w<<<64, 256, 0, stream>>>(W2 + (size_t)l * DIM * DIM, f2, f2 + 16384);
  }

  // ---- CSR build (parallel scan)
  hipMemsetAsync(cnt, 0, sizeof(int) * (size_t)N_NODES, stream);
  hipMemsetAsync(cur, 0, sizeof(int) * (size_t)N_NODES, stream);
  hipMemsetAsync(stats, 0, sizeof(float) * 1536, stream);
  edge_hist<<<edge_grid, 256, 0, stream>>>(ei + E, cnt, E);
  scan1<<<SCAN_B, 256, 0, stream>>>(cnt, row_ptr, bsum);
  scan2<<<1, 64, 0, stream>>>(bsum, boff, row_ptr + N_NODES);
  scan3<<<SCAN_B, 256, 0, stream>>>(row_ptr, boff);
  edge_fill<<<edge_grid, 256, 0, stream>>>(ei, ei + E, row_ptr, cur, srcl, E);

  const float* hin = x;   // aggregate input (x, then t2 of previous layer)
  float* zb = bufA;       // aggregate out / gemm1 in; gemm2 out
  float* tb = bufB;       // gemm1 out / gemm2 in
  for (int l = 0; l < 3; ++l) {
    unsigned short* f1 = wf + (size_t)(2 * l) * 32768;
    unsigned short* f2 = wf + (size_t)(2 * l + 1) * 32768;
    float* stL = stats + l * 512;  // sum1[128] sq1[128] sum2[128] sq2[128]
    if (l == 0)
      aggregate_combine<0><<<agg_grid, 256, 0, stream>>>(
          hin, row_ptr, srcl, eps + l, nullptr, nullptr, nullptr, zb);
    else
      aggregate_combine<1><<<agg_grid, 256, 0, stream>>>(
          hin, row_ptr, srcl, eps + l, stats + (l - 1) * 512 + 256,
          g2 + (l - 1) * DIM, bb2 + (l - 1) * DIM, zb);
    gemm_mfma<2><<<gemm_grid, 256, 0, stream>>>(
        zb, nullptr, nullptr, nullptr, f1, f1 + 16384, b1 + l * DIM, tb, stL);
    gemm_mfma<1><<<gemm_grid, 256, 0, stream>>>(
        tb, stL, g1 + l * DIM, bb1 + l * DIM, f2, f2 + 16384, b2 + l * DIM, zb,
        stL + 256);
    hin = zb;           // this layer's t2
    float* tmp = zb;    // ping-pong so next aggregate never writes its input
    zb = tb;
    tb = tmp;
  }
  apply_bn<<<apply_grid, 256, 0, stream>>>(hin, stats + 2 * 512 + 256,
                                           g2 + 2 * DIM, bb2 + 2 * DIM,
                                           (float*)d_out);
}